// Round 24
// baseline (900.677 us; speedup 1.0000x reference)
//
#include <hip/hip_runtime.h>
#include <float.h>

#define M_TOK 16384   // B*T
#define DIM   256
#define NCODE 1024
#define NQ    8
#define FEAT  756
#define DSCALE 0.00375f   // DELTA = DSCALE*sqrt(t1): == 0.06 at q=0, ~23 sigma of bf16 noise
#define LCAP  1536
#define L2CAP 384

using short8 = __attribute__((ext_vector_type(8))) short;  // 8 bf16
using f32x4  = __attribute__((ext_vector_type(4))) float;

__device__ __forceinline__ float fm(float a, float b) { return __fmul_rn(a, b); }
__device__ __forceinline__ float fa(float a, float b) { return __fadd_rn(a, b); }
__device__ __forceinline__ float fs(float a, float b) { return __fsub_rn(a, b); }

__device__ __forceinline__ unsigned fkey(float f) {
  unsigned b = __float_as_uint(f);
  return (b & 0x80000000u) ? ~b : (b | 0x80000000u);
}
__device__ __forceinline__ float funkey(unsigned k) {
  unsigned b = (k & 0x80000000u) ? (k & 0x7FFFFFFFu) : ~k;
  return __uint_as_float(b);
}
__device__ __forceinline__ unsigned short bf16rne(float x) {
  unsigned b = __float_as_uint(x);
  return (unsigned short)((b + 0x7FFFu + ((b >> 16) & 1u)) >> 16);
}

// direct global->LDS, 16B per lane; lptr wave-uniform base, gptr per-lane
__device__ __forceinline__ void gload_lds16(const void* g, void* l) {
  __builtin_amdgcn_global_load_lds(
      (const __attribute__((address_space(1))) unsigned int*)g,
      (__attribute__((address_space(3))) unsigned int*)l, 16, 0, 0);
}

// ---- numpy pairwise_sum (SSE2-npyv) of squares ----
__device__ float pairwise128_sq(const float* a) {
  float V[8][4];
#pragma unroll
  for (int j = 0; j < 8; ++j)
#pragma unroll
    for (int l = 0; l < 4; ++l) { float x = a[4 * j + l]; V[j][l] = fm(x, x); }
#pragma unroll
  for (int t = 1; t < 4; ++t)
#pragma unroll
    for (int j = 0; j < 8; ++j)
#pragma unroll
      for (int l = 0; l < 4; ++l) {
        float x = a[32 * t + 4 * j + l];
        V[j][l] = fa(V[j][l], fm(x, x));
      }
  float W[4];
#pragma unroll
  for (int l = 0; l < 4; ++l) {
    float p01 = fa(V[0][l], V[1][l]), p23 = fa(V[2][l], V[3][l]);
    float p45 = fa(V[4][l], V[5][l]), p67 = fa(V[6][l], V[7][l]);
    W[l] = fa(fa(p01, p23), fa(p45, p67));
  }
  return fa(fa(W[0], W[2]), fa(W[1], W[3]));
}
__device__ float pairwise256_sq(const float* a) {
  return fa(pairwise128_sq(a), pairwise128_sq(a + 128));
}

// ---- z: np-exact chain per (m,d); 16 tok/block, 4 tok/thread, 12-row dbuf ----
__global__ __launch_bounds__(256) void k_z(const float* __restrict__ in,
                                           const float* __restrict__ w_in,
                                           float* __restrict__ residual) {
  const int m0 = blockIdx.x * 16;
  __shared__ __align__(16) float xp[16][FEAT];       // packed: xp[t][c*252+f] 48384B
  __shared__ __align__(16) float wsb[2][12][256];    // 24576 B
  for (int i = threadIdx.x; i < 16 * FEAT; i += 256) {
    int t = i / FEAT, F = i - t * FEAT;              // input flat: F = f*3+c
    int f = F / 3, c = F - f * 3;
    xp[t][c * 252 + f] = in[(size_t)m0 * FEAT + i];
  }
  const int dg = threadIdx.x & 63;
  const int tg = threadIdx.x >> 6;
#pragma unroll
  for (int k = 0; k < 3; ++k) {
    int fi = threadIdx.x + k * 256, row = fi >> 6, col = (fi & 63) * 4;
    *reinterpret_cast<float4*>(&wsb[0][row][col]) =
        *reinterpret_cast<const float4*>(&w_in[(size_t)row * DIM + col]);
  }
  __syncthreads();
  float4 a0 = {0.f, 0.f, 0.f, 0.f}, a1 = {0.f, 0.f, 0.f, 0.f};
  float4 a2 = {0.f, 0.f, 0.f, 0.f}, a3 = {0.f, 0.f, 0.f, 0.f};
  const float* xr0 = &xp[tg * 4 + 0][0];
  const float* xr1 = &xp[tg * 4 + 1][0];
  const float* xr2 = &xp[tg * 4 + 2][0];
  const float* xr3 = &xp[tg * 4 + 3][0];
  int cur = 0;
  for (int ch = 0; ch < 63; ++ch) {            // F_lin = ch*12 + j, ascending
    float4 nx[3];
    const bool hn = (ch + 1 < 63);
    if (hn) {
#pragma unroll
      for (int k = 0; k < 3; ++k) {
        int fi = threadIdx.x + k * 256, row = fi >> 6, col = (fi & 63) * 4;
        nx[k] = *reinterpret_cast<const float4*>(
            &w_in[((size_t)(ch + 1) * 12 + row) * DIM + col]);
      }
    }
#pragma unroll
    for (int j4 = 0; j4 < 3; ++j4) {
      float4 x0v = *reinterpret_cast<const float4*>(&xr0[ch * 12 + j4 * 4]);
      float4 x1v = *reinterpret_cast<const float4*>(&xr1[ch * 12 + j4 * 4]);
      float4 x2v = *reinterpret_cast<const float4*>(&xr2[ch * 12 + j4 * 4]);
      float4 x3v = *reinterpret_cast<const float4*>(&xr3[ch * 12 + j4 * 4]);
      float xs0[4] = {x0v.x, x0v.y, x0v.z, x0v.w};
      float xs1[4] = {x1v.x, x1v.y, x1v.z, x1v.w};
      float xs2[4] = {x2v.x, x2v.y, x2v.z, x2v.w};
      float xs3[4] = {x3v.x, x3v.y, x3v.z, x3v.w};
#pragma unroll
      for (int jj = 0; jj < 4; ++jj) {
        float4 w4 = *reinterpret_cast<const float4*>(&wsb[cur][j4 * 4 + jj][dg * 4]);
        float x0 = xs0[jj], x1 = xs1[jj], x2 = xs2[jj], x3 = xs3[jj];
        a0.x = fa(a0.x, fm(x0, w4.x)); a0.y = fa(a0.y, fm(x0, w4.y));
        a0.z = fa(a0.z, fm(x0, w4.z)); a0.w = fa(a0.w, fm(x0, w4.w));
        a1.x = fa(a1.x, fm(x1, w4.x)); a1.y = fa(a1.y, fm(x1, w4.y));
        a1.z = fa(a1.z, fm(x1, w4.z)); a1.w = fa(a1.w, fm(x1, w4.w));
        a2.x = fa(a2.x, fm(x2, w4.x)); a2.y = fa(a2.y, fm(x2, w4.y));
        a2.z = fa(a2.z, fm(x2, w4.z)); a2.w = fa(a2.w, fm(x2, w4.w));
        a3.x = fa(a3.x, fm(x3, w4.x)); a3.y = fa(a3.y, fm(x3, w4.y));
        a3.z = fa(a3.z, fm(x3, w4.z)); a3.w = fa(a3.w, fm(x3, w4.w));
      }
    }
    if (hn) {
#pragma unroll
      for (int k = 0; k < 3; ++k) {
        int fi = threadIdx.x + k * 256, row = fi >> 6, col = (fi & 63) * 4;
        *reinterpret_cast<float4*>(&wsb[cur ^ 1][row][col]) = nx[k];
      }
    }
    __syncthreads();
    cur ^= 1;
  }
  *reinterpret_cast<float4*>(&residual[(size_t)(m0 + tg * 4 + 0) * DIM + dg * 4]) = a0;
  *reinterpret_cast<float4*>(&residual[(size_t)(m0 + tg * 4 + 1) * DIM + dg * 4]) = a1;
  *reinterpret_cast<float4*>(&residual[(size_t)(m0 + tg * 4 + 2) * DIM + dg * 4]) = a2;
  *reinterpret_cast<float4*>(&residual[(size_t)(m0 + tg * 4 + 3) * DIM + dg * 4]) = a3;
}

// ---- codebook row norms (np pairwise) ----
__global__ __launch_bounds__(256) void k_cbnorm(const float* __restrict__ cb,
                                                float* __restrict__ cbn) {
  int row = blockIdx.x * 256 + threadIdx.x;
  if (row >= NQ * NCODE) return;
  cbn[row] = pairwise256_sq(&cb[(size_t)row * DIM]);
}

// ---- codebook f32 -> bf16 bits ----
__global__ __launch_bounds__(256) void k_cb16(const float* __restrict__ cb,
                                              unsigned short* __restrict__ cb16) {
  size_t i = (size_t)blockIdx.x * 1024 + (size_t)threadIdx.x * 4;
  float4 v = *reinterpret_cast<const float4*>(&cb[i]);
  ushort4 o;
  o.x = bf16rne(v.x); o.y = bf16rne(v.y); o.z = bf16rne(v.z); o.w = bf16rne(v.w);
  *reinterpret_cast<ushort4*>(&cb16[i]) = o;
}

// ---- w_out transpose -> bf16 wT16[768][256] ----
__global__ __launch_bounds__(256) void k_wt(const float* __restrict__ w_out,
                                            unsigned short* __restrict__ wT16) {
  int n = blockIdx.x, k = threadIdx.x;
  float v = (n < FEAT) ? w_out[(size_t)k * FEAT + n] : 0.f;
  wT16[(size_t)n * DIM + k] = bf16rne(v);
}

// ---- fused 8-step VQ: 32 tokens/block, 4 waves, 32-code tiles; 2 blocks/CU ----
__global__ __launch_bounds__(256) void k_vq8(
    const unsigned short* __restrict__ cb16, const float* __restrict__ cb,
    const float* __restrict__ cbn, const float* __restrict__ residual,
    float* __restrict__ allq, float* __restrict__ idxout) {
  __shared__ __align__(16) unsigned short BsLin[2 * 32 * 256];   // 32768 B
  __shared__ __align__(16) float res_s[32][260];                 // 33280 B
  __shared__ float cbn_s[NCODE];                                 //  4096 B
  __shared__ unsigned list[LCAP];                                //  6144 B
  __shared__ unsigned list2[L2CAP];                              //  1536 B
  __shared__ unsigned fbs_u[32];
  __shared__ float t1_s[32], dlt_s[32];
  __shared__ unsigned long long best64_s[32];
  __shared__ unsigned lcnt, l2cnt, ovf;
  const int m0 = blockIdx.x * 32;
  const int tid = threadIdx.x, w = tid >> 6, lane = tid & 63;
  const int lrow = lane & 15, lk = lane >> 4;
  const int wg = w & 1, grp = w >> 1;          // token-half, code-half

  // load this block's residual tile into LDS (coalesced)
  for (int i = tid; i < 32 * 64; i += 256) {   // 2048 float4s
    int tok = i >> 6, c4 = i & 63;
    float4 v = *reinterpret_cast<const float4*>(&residual[(size_t)(m0 + tok) * DIM + c4 * 4]);
    *reinterpret_cast<float4*>(&res_s[tok][c4 * 4]) = v;
  }
  __syncthreads();
  if (tid < 32) {
    t1_s[tid] = pairwise256_sq(&res_s[tid][0]);   // np token norm
    best64_s[tid] = 0xFFFFFFFFFFFFFFFFull;
  }
  __syncthreads();

  for (int q = 0; q < NQ; ++q) {
    const unsigned short* cbq16 = cb16 + (size_t)q * NCODE * DIM;
    const float* cbqf = cb + (size_t)q * NCODE * DIM;

    for (int i = tid; i < NCODE; i += 256) cbn_s[i] = cbn[q * NCODE + i];
    if (tid < 32) {
      dlt_s[tid] = fmaxf(DSCALE * sqrtf(fmaxf(t1_s[tid], 0.f)), 1e-5f);
      fbs_u[tid] = 0xFFFFFFFFu;
    }
    if (tid == 0) { lcnt = 0; l2cnt = 0; ovf = 0; }

    // A fragments from LDS residual: token = wg*16 + lrow
    short8 afr[8];
    {
      const float* rrow = &res_s[wg * 16 + lrow][0];
#pragma unroll
      for (int s = 0; s < 8; ++s) {
        float4 x0 = *reinterpret_cast<const float4*>(&rrow[s * 32 + lk * 8]);
        float4 x1 = *reinterpret_cast<const float4*>(&rrow[s * 32 + lk * 8 + 4]);
        short8 t;
        t[0] = (short)bf16rne(x0.x); t[1] = (short)bf16rne(x0.y);
        t[2] = (short)bf16rne(x0.z); t[3] = (short)bf16rne(x0.w);
        t[4] = (short)bf16rne(x1.x); t[5] = (short)bf16rne(x1.y);
        t[6] = (short)bf16rne(x1.z); t[7] = (short)bf16rne(x1.w);
        afr[s] = t;
      }
    }

    // stage one 32-code tile (16KB): 1024 chunks of 16B, 256 lanes x 4
#define STAGE(CT, B)                                                             \
    {                                                                            \
      _Pragma("unroll")                                                          \
      for (int k_ = 0; k_ < 4; ++k_) {                                           \
        int c_ = (w * 4 + k_) * 64 + lane;            /* 0..1023 */              \
        int row_ = c_ >> 5, c16_ = c_ & 31;                                      \
        const unsigned short* g_ =                                               \
            &cbq16[(size_t)((CT) * 32 + row_) * 256 + (size_t)((c16_ ^ (row_ & 7)) * 8)]; \
        unsigned short* l_ = &BsLin[(B) * 8192 + (w * 4 + k_) * 512];            \
        gload_lds16(g_, l_);                                                     \
      }                                                                          \
    }

    STAGE(0, 0);
    __syncthreads();

    const int tokbase = wg * 16 + lk * 4;
    float dl[4];
#pragma unroll
    for (int r = 0; r < 4; ++r) dl[r] = dlt_s[tokbase + r];
    float runmin[4] = {FLT_MAX, FLT_MAX, FLT_MAX, FLT_MAX};
    int runcode[4] = {0, 0, 0, 0};

#define PUSH(PD, PC, R)                                                          \
    {                                                                            \
      unsigned idx_ = atomicAdd(&lcnt, 1u);                                      \
      if (idx_ < LCAP)                                                           \
        list[idx_] = (fkey(PD) & 0xFFFF0000u) |                                  \
                     ((unsigned)(tokbase + (R)) << 10) | (unsigned)(PC);         \
      else                                                                       \
        ovf = 1u;                                                                \
    }

    for (int ct = 0; ct < 32; ++ct) {
      const int b = ct & 1;
      if (ct + 1 < 32) STAGE(ct + 1, b ^ 1);

      f32x4 acc = (f32x4){0.f, 0.f, 0.f, 0.f};
#pragma unroll
      for (int s = 0; s < 8; ++s) {
        const int row = grp * 16 + lrow;
        const int chunk = (s * 4 + lk) ^ (lrow & 7);
        short8 bfr = *reinterpret_cast<const short8*>(
            &BsLin[b * 8192 + (size_t)row * 256 + chunk * 8]);
        acc = __builtin_amdgcn_mfma_f32_16x16x32_bf16(afr[s], bfr, acc, 0, 0, 0);
      }

      const int code = ct * 32 + grp * 16 + lrow;
      const float t3 = cbn_s[code];
#pragma unroll
      for (int r = 0; r < 4; ++r) {
        const float d = t3 - 2.0f * acc[r];
        if (d < runmin[r]) {
          if (runmin[r] <= d + dl[r]) PUSH(runmin[r], runcode[r], r);
          runmin[r] = d; runcode[r] = code;
        } else if (d <= runmin[r] + dl[r]) {
          PUSH(d, code, r);
        }
      }
      __syncthreads();
    }

    // wave-level fast best FIRST; final runmin pushed only if near it
    float fb[4] = {runmin[0], runmin[1], runmin[2], runmin[3]};
#pragma unroll
    for (int off = 8; off >= 1; off >>= 1)
#pragma unroll
      for (int r = 0; r < 4; ++r)
        fb[r] = fminf(fb[r], __shfl_xor(fb[r], off, 64));
#pragma unroll
    for (int r = 0; r < 4; ++r)
      if (runmin[r] <= fb[r] + dl[r]) PUSH(runmin[r], runcode[r], r);
    if (lrow == 0)
#pragma unroll
      for (int r = 0; r < 4; ++r)
        atomicMin(&fbs_u[tokbase + r], fkey(fb[r]));
    __syncthreads();

    // filter list -> survivors
    {
      unsigned n = lcnt; if (n > LCAP) n = LCAP;
      for (unsigned i = tid; i < n; i += 256) {
        unsigned e = list[i];
        unsigned tok = (e >> 10) & 31u;
        float df = funkey(e & 0xFFFF0000u);
        if (df <= funkey(fbs_u[tok]) + dlt_s[tok]) {
          unsigned j = atomicAdd(&l2cnt, 1u);
          if (j < L2CAP) list2[j] = e & 0x7FFFu;
          else ovf = 1u;
        }
      }
    }
    __syncthreads();

    // cooperative np-exact repair: 4 lanes per candidate (LDS residual)
    {
      unsigned n2 = l2cnt; if (n2 > L2CAP) n2 = L2CAP;
      const int j4 = lane & 3, g = lane >> 2;
      for (unsigned i0 = (unsigned)w * 16u; i0 < n2; i0 += 64u) {
        unsigned ci = i0 + (unsigned)g;
        bool act = ci < n2;
        unsigned ent = act ? list2[ci] : 0u;
        unsigned tok = (ent >> 10) & 31u, code = ent & 1023u;
        const float* rr = &res_s[tok][0];
        const float* cc2 = &cbqf[(size_t)code * DIM];
        float L = 0.f;
#pragma unroll 8
        for (int t = 0; t < 64; ++t)
          L = fa(L, fm(rr[4 * t + j4], cc2[4 * t + j4]));
        float tmp = fa(L, __shfl_xor(L, 2, 64));
        float e4 = fa(tmp, __shfl_xor(tmp, 1, 64));
        if (act && j4 == 0) {
          float dn = fa(fs(t1_s[tok], fa(e4, e4)), cbn_s[code]);
          atomicMin(&best64_s[tok],
                    ((unsigned long long)fkey(dn) << 32) | code);
        }
      }
    }
    __syncthreads();

    // COLD fallback: full np-exact scan (list overflow; never in practice)
    if (ovf) {
      const int j4 = lane & 3, g = lane >> 2;
      for (int t = 0; t < 8; ++t) {
        const int tok = w * 8 + t;
        const float* rr = &res_s[tok][0];
        for (int c0 = 0; c0 < NCODE; c0 += 16) {
          int code = c0 + g;
          const float* cc2 = &cbqf[(size_t)code * DIM];
          float L = 0.f;
          for (int tt = 0; tt < 64; ++tt)
            L = fa(L, fm(rr[4 * tt + j4], cc2[4 * tt + j4]));
          float tmp = fa(L, __shfl_xor(L, 2, 64));
          float e4 = fa(tmp, __shfl_xor(tmp, 1, 64));
          if (j4 == 0) {
            float dn = fa(fs(t1_s[tok], fa(e4, e4)), cbn_s[code]);
            atomicMin(&best64_s[tok],
                      ((unsigned long long)fkey(dn) << 32) | (unsigned)code);
          }
        }
      }
      __syncthreads();
    }

    // update: residual step in LDS (np fs), allq, idx; t1 via shuffle tree
    for (int t = 0; t < 8; ++t) {
      const int tok = w * 8 + t;
      const size_t m = (size_t)m0 + tok;
      const int ci = (int)(best64_s[tok] & 0xFFFFFFFFull);
      const float4 cv = *reinterpret_cast<const float4*>(&cbqf[(size_t)ci * DIM + lane * 4]);
      float4 r = *reinterpret_cast<const float4*>(&res_s[tok][lane * 4]);
      r.x = fs(r.x, cv.x); r.y = fs(r.y, cv.y); r.z = fs(r.z, cv.z); r.w = fs(r.w, cv.w);
      *reinterpret_cast<float4*>(&res_s[tok][lane * 4]) = r;
      *reinterpret_cast<float4*>(&allq[((size_t)q * M_TOK + m) * DIM + lane * 4]) = cv;
      float qs[4] = {fm(r.x, r.x), fm(r.y, r.y), fm(r.z, r.z), fm(r.w, r.w)};
      float W[4];
#pragma unroll
      for (int l = 0; l < 4; ++l) {
        float v = qs[l];
        float s1 = __shfl_down(v, 8, 64);
        float s2 = __shfl_down(v, 16, 64);
        float s3 = __shfl_down(v, 24, 64);
        float V = fa(fa(fa(v, s1), s2), s3);
        float A = fa(V, __shfl_down(V, 1, 64));
        float B = fa(A, __shfl_down(A, 2, 64));
        W[l] = fa(B, __shfl_down(B, 4, 64));
      }
      float hsum = fa(fa(W[0], W[2]), fa(W[1], W[3]));
      float up = __shfl(hsum, 32, 64);
      if (lane == 0) {
        t1_s[tok] = fa(hsum, up);
        best64_s[tok] = 0xFFFFFFFFFFFFFFFFull;
        idxout[m * NQ + q] = (float)ci;
      }
    }
    __syncthreads();   // res_s/t1_s updates visible for next q
#undef PUSH
#undef STAGE
  }
}

// ---- quantized = relu( (sum_q allq) @ w_out ), MFMA bf16; one block = 64 tokens ----
__global__ __launch_bounds__(256) void k_gemm_out(const float* __restrict__ allq,
                                                  const unsigned short* __restrict__ wT16,
                                                  float* __restrict__ C) {
  __shared__ __align__(16) unsigned short As[64][264];
  __shared__ __align__(16) unsigned short Bs[64][264];
  const int m0 = blockIdx.x * 64;
  const int tid = threadIdx.x, w = tid >> 6, lane = tid & 63;
  const int lrow = lane & 15, lk = lane >> 4;

#pragma unroll
  for (int k4 = 0; k4 < 16; ++k4) {
    int f4 = tid + k4 * 256;
    int tok = f4 >> 6, dseg = f4 & 63;
    float4 v = {0.f, 0.f, 0.f, 0.f};
#pragma unroll
    for (int qq = 0; qq < NQ; ++qq) {
      float4 t = *reinterpret_cast<const float4*>(
          &allq[((size_t)qq * M_TOK + m0 + tok) * DIM + dseg * 4]);
      v.x = fa(v.x, t.x); v.y = fa(v.y, t.y); v.z = fa(v.z, t.z); v.w = fa(v.w, t.w);
    }
    ushort4 o;
    o.x = bf16rne(v.x); o.y = bf16rne(v.y); o.z = bf16rne(v.z); o.w = bf16rne(v.w);
    *reinterpret_cast<ushort4*>(&As[tok][dseg * 4]) = o;
  }
  __syncthreads();

  short8 afr[8];
#pragma unroll
  for (int s = 0; s < 8; ++s)
    afr[s] = *reinterpret_cast<const short8*>(&As[w * 16 + lrow][s * 32 + lk * 8]);

  for (int nt = 0; nt < 12; ++nt) {
    const int n0 = nt * 64;
    __syncthreads();
    {
      int r = tid >> 2, seg = tid & 3;
      const uint4* src = reinterpret_cast<const uint4*>(&wT16[(size_t)(n0 + r) * DIM + seg * 64]);
      uint4* dst = reinterpret_cast<uint4*>(&Bs[r][seg * 64]);
#pragma unroll
      for (int u = 0; u < 8; ++u) dst[u] = src[u];
    }
    __syncthreads();

    f32x4 acc[4];
#pragma unroll
    for (int f = 0; f < 4; ++f) acc[f] = (f32x4){0.f, 0.f, 0.f, 0.f};
#pragma unroll
    for (int s = 0; s < 8; ++s) {
#pragma unroll
      for (int f = 0; f < 4; ++f) {
        short8 bfr = *reinterpret_cast<const short8*>(&Bs[f * 16 + lrow][s * 32 + lk * 8]);
        acc[f] = __builtin_amdgcn_mfma_f32_16x16x32_bf16(afr[s], bfr, acc[f], 0, 0, 0);
      }
    }

#pragma unroll
    for (int f = 0; f < 4; ++f) {
      const int col = n0 + f * 16 + lrow;
      if (col < FEAT) {
#pragma unroll
        for (int r = 0; r < 4; ++r)
          C[(size_t)(m0 + w * 16 + lk * 4 + r) * FEAT + col] = fmaxf(acc[f][r], 0.f);
      }
    }
  }
}

extern "C" void kernel_launch(void* const* d_in, const int* in_sizes, int n_in,
                              void* d_out, int out_size, void* d_ws, size_t ws_size,
                              hipStream_t stream) {
  int i_inputs = 0, i_cb = 1, iA = 2, iB = 3;
  {
    int a = -1, b = -1, ii = -1, ic = -1;
    for (int i = 0; i < n_in; ++i) {
      if (in_sizes[i] == M_TOK * FEAT) ii = i;
      else if (in_sizes[i] == NQ * NCODE * DIM) ic = i;
      else if (in_sizes[i] == FEAT * DIM) { if (a < 0) a = i; else b = i; }
    }
    if (ii >= 0 && ic >= 0 && a >= 0 && b >= 0) { i_inputs = ii; i_cb = ic; iA = a; iB = b; }
  }
  const float* inputs = (const float*)d_in[i_inputs];
  const float* cb     = (const float*)d_in[i_cb];
  const float* w_in   = (const float*)d_in[iA];
  const float* w_out  = (const float*)d_in[iB];

  float* out       = (float*)d_out;
  float* quantized = out;                                 // 16384*756
  float* allq      = out + (size_t)M_TOK * FEAT;          // 8*16384*256
  float* idxout    = allq + (size_t)NQ * M_TOK * DIM;     // 16384*8

  // residual (16.8MB) lives in the quantized region (read once by k_vq8).
  float* residual = quantized;

  // Small scratch in d_ws (~4.8 MB). k_gemm_out reads only allq (output) + wT16 (ws).
  char* ws = (char*)d_ws;
  unsigned short*     cb16   = (unsigned short*)(ws);                 // 4,194,304 B
  unsigned short*     wT16   = (unsigned short*)(ws + 4194304);       //   393,216 B
  float*              cbn    = (float*)(ws + 4587520);                //    32,768 B

  k_z<<<M_TOK / 16, 256, 0, stream>>>(inputs, w_in, residual);
  k_cbnorm<<<NQ * NCODE / 256, 256, 0, stream>>>(cb, cbn);
  k_cb16<<<NQ * NCODE * DIM / 1024, 256, 0, stream>>>(cb, cb16);
  k_wt<<<768, 256, 0, stream>>>(w_out, wT16);
  k_vq8<<<M_TOK / 32, 256, 0, stream>>>(cb16, cb, cbn, residual, allq, idxout);
  k_gemm_out<<<M_TOK / 64, 256, 0, stream>>>(allq, wT16, quantized);
}

// Round 25
// 534.682 us; speedup vs baseline: 1.6845x; 1.6845x over previous
//
#include <hip/hip_runtime.h>
#include <float.h>

#define M_TOK 16384   // B*T
#define DIM   256
#define NCODE 1024
#define NQ    8
#define FEAT  756
#define DSCALE 0.00375f   // DELTA = DSCALE*sqrt(t1): == 0.06 at q=0, ~23 sigma of bf16 noise
#define LCAP  2560
#define L2CAP 512

using short8 = __attribute__((ext_vector_type(8))) short;  // 8 bf16
using f32x4  = __attribute__((ext_vector_type(4))) float;

__device__ __forceinline__ float fm(float a, float b) { return __fmul_rn(a, b); }
__device__ __forceinline__ float fa(float a, float b) { return __fadd_rn(a, b); }
__device__ __forceinline__ float fs(float a, float b) { return __fsub_rn(a, b); }

__device__ __forceinline__ unsigned fkey(float f) {
  unsigned b = __float_as_uint(f);
  return (b & 0x80000000u) ? ~b : (b | 0x80000000u);
}
__device__ __forceinline__ float funkey(unsigned k) {
  unsigned b = (k & 0x80000000u) ? (k & 0x7FFFFFFFu) : ~k;
  return __uint_as_float(b);
}
__device__ __forceinline__ unsigned short bf16rne(float x) {
  unsigned b = __float_as_uint(x);
  return (unsigned short)((b + 0x7FFFu + ((b >> 16) & 1u)) >> 16);
}

// direct global->LDS, 16B per lane; lptr wave-uniform base, gptr per-lane
__device__ __forceinline__ void gload_lds16(const void* g, void* l) {
  __builtin_amdgcn_global_load_lds(
      (const __attribute__((address_space(1))) unsigned int*)g,
      (__attribute__((address_space(3))) unsigned int*)l, 16, 0, 0);
}

// ---- numpy pairwise_sum (SSE2-npyv) of squares ----
__device__ float pairwise128_sq(const float* a) {
  float V[8][4];
#pragma unroll
  for (int j = 0; j < 8; ++j)
#pragma unroll
    for (int l = 0; l < 4; ++l) { float x = a[4 * j + l]; V[j][l] = fm(x, x); }
#pragma unroll
  for (int t = 1; t < 4; ++t)
#pragma unroll
    for (int j = 0; j < 8; ++j)
#pragma unroll
      for (int l = 0; l < 4; ++l) {
        float x = a[32 * t + 4 * j + l];
        V[j][l] = fa(V[j][l], fm(x, x));
      }
  float W[4];
#pragma unroll
  for (int l = 0; l < 4; ++l) {
    float p01 = fa(V[0][l], V[1][l]), p23 = fa(V[2][l], V[3][l]);
    float p45 = fa(V[4][l], V[5][l]), p67 = fa(V[6][l], V[7][l]);
    W[l] = fa(fa(p01, p23), fa(p45, p67));
  }
  return fa(fa(W[0], W[2]), fa(W[1], W[3]));
}
__device__ float pairwise256_sq(const float* a) {
  return fa(pairwise128_sq(a), pairwise128_sq(a + 128));
}

// ---- z: np-exact chain per (m,d); 16 tok/block, 4 tok/thread, 12-row dbuf ----
__global__ __launch_bounds__(256) void k_z(const float* __restrict__ in,
                                           const float* __restrict__ w_in,
                                           float* __restrict__ residual) {
  const int m0 = blockIdx.x * 16;
  __shared__ __align__(16) float xp[16][FEAT];       // packed: xp[t][c*252+f] 48384B
  __shared__ __align__(16) float wsb[2][12][256];    // 24576 B
  for (int i = threadIdx.x; i < 16 * FEAT; i += 256) {
    int t = i / FEAT, F = i - t * FEAT;              // input flat: F = f*3+c
    int f = F / 3, c = F - f * 3;
    xp[t][c * 252 + f] = in[(size_t)m0 * FEAT + i];
  }
  const int dg = threadIdx.x & 63;
  const int tg = threadIdx.x >> 6;
#pragma unroll
  for (int k = 0; k < 3; ++k) {
    int fi = threadIdx.x + k * 256, row = fi >> 6, col = (fi & 63) * 4;
    *reinterpret_cast<float4*>(&wsb[0][row][col]) =
        *reinterpret_cast<const float4*>(&w_in[(size_t)row * DIM + col]);
  }
  __syncthreads();
  float4 a0 = {0.f, 0.f, 0.f, 0.f}, a1 = {0.f, 0.f, 0.f, 0.f};
  float4 a2 = {0.f, 0.f, 0.f, 0.f}, a3 = {0.f, 0.f, 0.f, 0.f};
  const float* xr0 = &xp[tg * 4 + 0][0];
  const float* xr1 = &xp[tg * 4 + 1][0];
  const float* xr2 = &xp[tg * 4 + 2][0];
  const float* xr3 = &xp[tg * 4 + 3][0];
  int cur = 0;
  for (int ch = 0; ch < 63; ++ch) {            // F_lin = ch*12 + j, ascending
    float4 nx[3];
    const bool hn = (ch + 1 < 63);
    if (hn) {
#pragma unroll
      for (int k = 0; k < 3; ++k) {
        int fi = threadIdx.x + k * 256, row = fi >> 6, col = (fi & 63) * 4;
        nx[k] = *reinterpret_cast<const float4*>(
            &w_in[((size_t)(ch + 1) * 12 + row) * DIM + col]);
      }
    }
#pragma unroll
    for (int j4 = 0; j4 < 3; ++j4) {
      float4 x0v = *reinterpret_cast<const float4*>(&xr0[ch * 12 + j4 * 4]);
      float4 x1v = *reinterpret_cast<const float4*>(&xr1[ch * 12 + j4 * 4]);
      float4 x2v = *reinterpret_cast<const float4*>(&xr2[ch * 12 + j4 * 4]);
      float4 x3v = *reinterpret_cast<const float4*>(&xr3[ch * 12 + j4 * 4]);
      float xs0[4] = {x0v.x, x0v.y, x0v.z, x0v.w};
      float xs1[4] = {x1v.x, x1v.y, x1v.z, x1v.w};
      float xs2[4] = {x2v.x, x2v.y, x2v.z, x2v.w};
      float xs3[4] = {x3v.x, x3v.y, x3v.z, x3v.w};
#pragma unroll
      for (int jj = 0; jj < 4; ++jj) {
        float4 w4 = *reinterpret_cast<const float4*>(&wsb[cur][j4 * 4 + jj][dg * 4]);
        float x0 = xs0[jj], x1 = xs1[jj], x2 = xs2[jj], x3 = xs3[jj];
        a0.x = fa(a0.x, fm(x0, w4.x)); a0.y = fa(a0.y, fm(x0, w4.y));
        a0.z = fa(a0.z, fm(x0, w4.z)); a0.w = fa(a0.w, fm(x0, w4.w));
        a1.x = fa(a1.x, fm(x1, w4.x)); a1.y = fa(a1.y, fm(x1, w4.y));
        a1.z = fa(a1.z, fm(x1, w4.z)); a1.w = fa(a1.w, fm(x1, w4.w));
        a2.x = fa(a2.x, fm(x2, w4.x)); a2.y = fa(a2.y, fm(x2, w4.y));
        a2.z = fa(a2.z, fm(x2, w4.z)); a2.w = fa(a2.w, fm(x2, w4.w));
        a3.x = fa(a3.x, fm(x3, w4.x)); a3.y = fa(a3.y, fm(x3, w4.y));
        a3.z = fa(a3.z, fm(x3, w4.z)); a3.w = fa(a3.w, fm(x3, w4.w));
      }
    }
    if (hn) {
#pragma unroll
      for (int k = 0; k < 3; ++k) {
        int fi = threadIdx.x + k * 256, row = fi >> 6, col = (fi & 63) * 4;
        *reinterpret_cast<float4*>(&wsb[cur ^ 1][row][col]) = nx[k];
      }
    }
    __syncthreads();
    cur ^= 1;
  }
  *reinterpret_cast<float4*>(&residual[(size_t)(m0 + tg * 4 + 0) * DIM + dg * 4]) = a0;
  *reinterpret_cast<float4*>(&residual[(size_t)(m0 + tg * 4 + 1) * DIM + dg * 4]) = a1;
  *reinterpret_cast<float4*>(&residual[(size_t)(m0 + tg * 4 + 2) * DIM + dg * 4]) = a2;
  *reinterpret_cast<float4*>(&residual[(size_t)(m0 + tg * 4 + 3) * DIM + dg * 4]) = a3;
}

// ---- codebook row norms (np pairwise) ----
__global__ __launch_bounds__(256) void k_cbnorm(const float* __restrict__ cb,
                                                float* __restrict__ cbn) {
  int row = blockIdx.x * 256 + threadIdx.x;
  if (row >= NQ * NCODE) return;
  cbn[row] = pairwise256_sq(&cb[(size_t)row * DIM]);
}

// ---- codebook f32 -> bf16 bits ----
__global__ __launch_bounds__(256) void k_cb16(const float* __restrict__ cb,
                                              unsigned short* __restrict__ cb16) {
  size_t i = (size_t)blockIdx.x * 1024 + (size_t)threadIdx.x * 4;
  float4 v = *reinterpret_cast<const float4*>(&cb[i]);
  ushort4 o;
  o.x = bf16rne(v.x); o.y = bf16rne(v.y); o.z = bf16rne(v.z); o.w = bf16rne(v.w);
  *reinterpret_cast<ushort4*>(&cb16[i]) = o;
}

// ---- w_out transpose -> bf16 wT16[768][256] ----
__global__ __launch_bounds__(256) void k_wt(const float* __restrict__ w_out,
                                            unsigned short* __restrict__ wT16) {
  int n = blockIdx.x, k = threadIdx.x;
  float v = (n < FEAT) ? w_out[(size_t)k * FEAT + n] : 0.f;
  wT16[(size_t)n * DIM + k] = bf16rne(v);
}

// ---- fused 8-step VQ: residual resident in LDS; per q: screen+repair+update ----
__global__ __launch_bounds__(512) void k_vq8(
    const unsigned short* __restrict__ cb16, const float* __restrict__ cb,
    const float* __restrict__ cbn, const float* __restrict__ residual,
    float* __restrict__ allq, float* __restrict__ idxout) {
  __shared__ __align__(16) unsigned short BsLin[2 * 64 * 256];   // 65536 B
  __shared__ __align__(16) float res_s[64][260];                 // 66560 B (pad 4)
  __shared__ float cbn_s[NCODE];                                 //  4096 B
  __shared__ unsigned list[LCAP];                                // 10240 B
  __shared__ unsigned list2[L2CAP];                              //  2048 B
  __shared__ unsigned fbs_u[64];
  __shared__ float t1_s[64], dlt_s[64];
  __shared__ unsigned long long best64_s[64];
  __shared__ unsigned lcnt, l2cnt, ovf;
  const int m0 = blockIdx.x * 64;
  const int tid = threadIdx.x, w = tid >> 6, lane = tid & 63;
  const int lrow = lane & 15, lk = lane >> 4;
  const int wg = w & 3, grp = w >> 2;          // token-quarter, f-half

  // load this block's residual tile into LDS (coalesced)
  for (int i = tid; i < 64 * 64; i += 512) {   // 4096 float4s
    int tok = i >> 6, c4 = i & 63;
    float4 v = *reinterpret_cast<const float4*>(&residual[(size_t)(m0 + tok) * DIM + c4 * 4]);
    *reinterpret_cast<float4*>(&res_s[tok][c4 * 4]) = v;
  }
  __syncthreads();
  if (tid < 64) {
    t1_s[tid] = pairwise256_sq(&res_s[tid][0]);   // np token norm
    best64_s[tid] = 0xFFFFFFFFFFFFFFFFull;
  }
  __syncthreads();

  for (int q = 0; q < NQ; ++q) {
    const unsigned short* cbq16 = cb16 + (size_t)q * NCODE * DIM;
    const float* cbqf = cb + (size_t)q * NCODE * DIM;

    for (int i = tid; i < NCODE; i += 512) cbn_s[i] = cbn[q * NCODE + i];
    if (tid < 64) {
      dlt_s[tid] = fmaxf(DSCALE * sqrtf(fmaxf(t1_s[tid], 0.f)), 1e-5f);
      fbs_u[tid] = 0xFFFFFFFFu;
    }
    if (tid == 0) { lcnt = 0; l2cnt = 0; ovf = 0; }

    // A fragments from LDS residual: token = wg*16 + lrow
    short8 afr[8];
    {
      const float* rrow = &res_s[wg * 16 + lrow][0];
#pragma unroll
      for (int s = 0; s < 8; ++s) {
        float4 x0 = *reinterpret_cast<const float4*>(&rrow[s * 32 + lk * 8]);
        float4 x1 = *reinterpret_cast<const float4*>(&rrow[s * 32 + lk * 8 + 4]);
        short8 t;
        t[0] = (short)bf16rne(x0.x); t[1] = (short)bf16rne(x0.y);
        t[2] = (short)bf16rne(x0.z); t[3] = (short)bf16rne(x0.w);
        t[4] = (short)bf16rne(x1.x); t[5] = (short)bf16rne(x1.y);
        t[6] = (short)bf16rne(x1.z); t[7] = (short)bf16rne(x1.w);
        afr[s] = t;
      }
    }

#define STAGE(CT, B)                                                             \
    {                                                                            \
      _Pragma("unroll")                                                          \
      for (int k_ = 0; k_ < 4; ++k_) {                                           \
        int c_ = (w * 4 + k_) * 64 + lane;                                       \
        int row_ = c_ >> 5, c16_ = c_ & 31;                                      \
        const unsigned short* g_ =                                               \
            &cbq16[(size_t)((CT) * 64 + row_) * 256 + (size_t)((c16_ ^ (row_ & 7)) * 8)]; \
        unsigned short* l_ = &BsLin[(B) * 16384 + (w * 4 + k_) * 512];           \
        gload_lds16(g_, l_);                                                     \
      }                                                                          \
    }

    STAGE(0, 0);
    __syncthreads();

    const int tokbase = wg * 16 + lk * 4;
    float dl[4];
#pragma unroll
    for (int r = 0; r < 4; ++r) dl[r] = dlt_s[tokbase + r];
    float runmin[4] = {FLT_MAX, FLT_MAX, FLT_MAX, FLT_MAX};
    int runcode[4] = {0, 0, 0, 0};

#define PUSH(PD, PC, R)                                                          \
    {                                                                            \
      unsigned idx_ = atomicAdd(&lcnt, 1u);                                      \
      if (idx_ < LCAP)                                                           \
        list[idx_] = (fkey(PD) & 0xFFFF0000u) |                                  \
                     ((unsigned)(tokbase + (R)) << 10) | (unsigned)(PC);         \
      else                                                                       \
        ovf = 1u;                                                                \
    }

    for (int ct = 0; ct < 16; ++ct) {
      const int b = ct & 1;
      if (ct + 1 < 16) STAGE(ct + 1, b ^ 1);

      f32x4 acc[2];
      acc[0] = (f32x4){0.f, 0.f, 0.f, 0.f};
      acc[1] = (f32x4){0.f, 0.f, 0.f, 0.f};
#pragma unroll
      for (int s = 0; s < 8; ++s) {
#pragma unroll
        for (int f2 = 0; f2 < 2; ++f2) {
          const int f = grp * 2 + f2;
          const int row = f * 16 + lrow;
          const int chunk = (s * 4 + lk) ^ (lrow & 7);
          short8 bfr = *reinterpret_cast<const short8*>(
              &BsLin[b * 16384 + (size_t)row * 256 + chunk * 8]);
          acc[f2] = __builtin_amdgcn_mfma_f32_16x16x32_bf16(afr[s], bfr, acc[f2], 0, 0, 0);
        }
      }

#pragma unroll
      for (int f2 = 0; f2 < 2; ++f2) {
        const int code = ct * 64 + (grp * 2 + f2) * 16 + lrow;
        const float t3 = cbn_s[code];
#pragma unroll
        for (int r = 0; r < 4; ++r) {
          const float d = t3 - 2.0f * acc[f2][r];
          if (d < runmin[r]) {
            if (runmin[r] <= d + dl[r]) PUSH(runmin[r], runcode[r], r);
            runmin[r] = d; runcode[r] = code;
          } else if (d <= runmin[r] + dl[r]) {
            PUSH(d, code, r);
          }
        }
      }
      __syncthreads();
    }

    // wave-level fast best FIRST; final runmin pushed only if near it
    float fb[4] = {runmin[0], runmin[1], runmin[2], runmin[3]};
#pragma unroll
    for (int off = 8; off >= 1; off >>= 1)
#pragma unroll
      for (int r = 0; r < 4; ++r)
        fb[r] = fminf(fb[r], __shfl_xor(fb[r], off, 64));
#pragma unroll
    for (int r = 0; r < 4; ++r)
      if (runmin[r] <= fb[r] + dl[r]) PUSH(runmin[r], runcode[r], r);
    if (lrow == 0)
#pragma unroll
      for (int r = 0; r < 4; ++r)
        atomicMin(&fbs_u[tokbase + r], fkey(fb[r]));
    __syncthreads();

    // filter list -> survivors
    {
      unsigned n = lcnt; if (n > LCAP) n = LCAP;
      for (unsigned i = tid; i < n; i += 512) {
        unsigned e = list[i];
        unsigned tok = (e >> 10) & 63u;
        float df = funkey(e & 0xFFFF0000u);
        if (df <= funkey(fbs_u[tok]) + dlt_s[tok]) {
          unsigned j = atomicAdd(&l2cnt, 1u);
          if (j < L2CAP) list2[j] = e & 0xFFFFu;
          else ovf = 1u;
        }
      }
    }
    __syncthreads();

    // cooperative np-exact repair: 4 lanes per candidate (LDS residual)
    {
      unsigned n2 = l2cnt; if (n2 > L2CAP) n2 = L2CAP;
      const int j4 = lane & 3, g = lane >> 2;
      for (unsigned i0 = (unsigned)w * 16u; i0 < n2; i0 += 128u) {
        unsigned ci = i0 + (unsigned)g;
        bool act = ci < n2;
        unsigned ent = act ? list2[ci] : 0u;
        unsigned tok = (ent >> 10) & 63u, code = ent & 1023u;
        const float* rr = &res_s[tok][0];
        const float* cc2 = &cbqf[(size_t)code * DIM];
        float L = 0.f;
#pragma unroll 8
        for (int t = 0; t < 64; ++t)
          L = fa(L, fm(rr[4 * t + j4], cc2[4 * t + j4]));
        float tmp = fa(L, __shfl_xor(L, 2, 64));
        float e4 = fa(tmp, __shfl_xor(tmp, 1, 64));
        if (act && j4 == 0) {
          float dn = fa(fs(t1_s[tok], fa(e4, e4)), cbn_s[code]);
          atomicMin(&best64_s[tok],
                    ((unsigned long long)fkey(dn) << 32) | code);
        }
      }
    }
    __syncthreads();

    // COLD fallback: full np-exact scan (list overflow; never in practice)
    if (ovf) {
      const int j4 = lane & 3, g = lane >> 2;
      for (int t = 0; t < 8; ++t) {
        const int tok = w * 8 + t;
        const float* rr = &res_s[tok][0];
        for (int c0 = 0; c0 < NCODE; c0 += 16) {
          int code = c0 + g;
          const float* cc2 = &cbqf[(size_t)code * DIM];
          float L = 0.f;
          for (int tt = 0; tt < 64; ++tt)
            L = fa(L, fm(rr[4 * tt + j4], cc2[4 * tt + j4]));
          float tmp = fa(L, __shfl_xor(L, 2, 64));
          float e4 = fa(tmp, __shfl_xor(tmp, 1, 64));
          if (j4 == 0) {
            float dn = fa(fs(t1_s[tok], fa(e4, e4)), cbn_s[code]);
            atomicMin(&best64_s[tok],
                      ((unsigned long long)fkey(dn) << 32) | (unsigned)code);
          }
        }
      }
      __syncthreads();
    }

    // update: residual step in LDS (np fs), allq, idx; t1 via shuffle tree
    for (int t = 0; t < 8; ++t) {
      const int tok = w * 8 + t;
      const size_t m = (size_t)m0 + tok;
      const int ci = (int)(best64_s[tok] & 0xFFFFFFFFull);
      const float4 cv = *reinterpret_cast<const float4*>(&cbqf[(size_t)ci * DIM + lane * 4]);
      float4 r = *reinterpret_cast<const float4*>(&res_s[tok][lane * 4]);
      r.x = fs(r.x, cv.x); r.y = fs(r.y, cv.y); r.z = fs(r.z, cv.z); r.w = fs(r.w, cv.w);
      *reinterpret_cast<float4*>(&res_s[tok][lane * 4]) = r;
      *reinterpret_cast<float4*>(&allq[((size_t)q * M_TOK + m) * DIM + lane * 4]) = cv;
      float qs[4] = {fm(r.x, r.x), fm(r.y, r.y), fm(r.z, r.z), fm(r.w, r.w)};
      float W[4];
#pragma unroll
      for (int l = 0; l < 4; ++l) {
        float v = qs[l];
        float s1 = __shfl_down(v, 8, 64);
        float s2 = __shfl_down(v, 16, 64);
        float s3 = __shfl_down(v, 24, 64);
        float V = fa(fa(fa(v, s1), s2), s3);
        float A = fa(V, __shfl_down(V, 1, 64));
        float B = fa(A, __shfl_down(A, 2, 64));
        W[l] = fa(B, __shfl_down(B, 4, 64));
      }
      float hsum = fa(fa(W[0], W[2]), fa(W[1], W[3]));
      float up = __shfl(hsum, 32, 64);
      if (lane == 0) {
        t1_s[tok] = fa(hsum, up);
        best64_s[tok] = 0xFFFFFFFFFFFFFFFFull;
        idxout[m * NQ + q] = (float)ci;
      }
    }
    __syncthreads();   // res_s/t1_s updates visible for next q
#undef PUSH
#undef STAGE
  }
}

// ---- quantized = relu( (sum_q allq) @ w_out ), MFMA bf16; one block = 64 tokens ----
__global__ __launch_bounds__(256) void k_gemm_out(const float* __restrict__ allq,
                                                  const unsigned short* __restrict__ wT16,
                                                  float* __restrict__ C) {
  __shared__ __align__(16) unsigned short As[64][264];
  __shared__ __align__(16) unsigned short Bs[64][264];
  const int m0 = blockIdx.x * 64;
  const int tid = threadIdx.x, w = tid >> 6, lane = tid & 63;
  const int lrow = lane & 15, lk = lane >> 4;

#pragma unroll
  for (int k4 = 0; k4 < 16; ++k4) {
    int f4 = tid + k4 * 256;
    int tok = f4 >> 6, dseg = f4 & 63;
    float4 v = {0.f, 0.f, 0.f, 0.f};
#pragma unroll
    for (int qq = 0; qq < NQ; ++qq) {
      float4 t = *reinterpret_cast<const float4*>(
          &allq[((size_t)qq * M_TOK + m0 + tok) * DIM + dseg * 4]);
      v.x = fa(v.x, t.x); v.y = fa(v.y, t.y); v.z = fa(v.z, t.z); v.w = fa(v.w, t.w);
    }
    ushort4 o;
    o.x = bf16rne(v.x); o.y = bf16rne(v.y); o.z = bf16rne(v.z); o.w = bf16rne(v.w);
    *reinterpret_cast<ushort4*>(&As[tok][dseg * 4]) = o;
  }
  __syncthreads();

  short8 afr[8];
#pragma unroll
  for (int s = 0; s < 8; ++s)
    afr[s] = *reinterpret_cast<const short8*>(&As[w * 16 + lrow][s * 32 + lk * 8]);

  for (int nt = 0; nt < 12; ++nt) {
    const int n0 = nt * 64;
    __syncthreads();
    {
      int r = tid >> 2, seg = tid & 3;
      const uint4* src = reinterpret_cast<const uint4*>(&wT16[(size_t)(n0 + r) * DIM + seg * 64]);
      uint4* dst = reinterpret_cast<uint4*>(&Bs[r][seg * 64]);
#pragma unroll
      for (int u = 0; u < 8; ++u) dst[u] = src[u];
    }
    __syncthreads();

    f32x4 acc[4];
#pragma unroll
    for (int f = 0; f < 4; ++f) acc[f] = (f32x4){0.f, 0.f, 0.f, 0.f};
#pragma unroll
    for (int s = 0; s < 8; ++s) {
#pragma unroll
      for (int f = 0; f < 4; ++f) {
        short8 bfr = *reinterpret_cast<const short8*>(&Bs[f * 16 + lrow][s * 32 + lk * 8]);
        acc[f] = __builtin_amdgcn_mfma_f32_16x16x32_bf16(afr[s], bfr, acc[f], 0, 0, 0);
      }
    }

#pragma unroll
    for (int f = 0; f < 4; ++f) {
      const int col = n0 + f * 16 + lrow;
      if (col < FEAT) {
#pragma unroll
        for (int r = 0; r < 4; ++r)
          C[(size_t)(m0 + w * 16 + lk * 4 + r) * FEAT + col] = fmaxf(acc[f][r], 0.f);
      }
    }
  }
}

extern "C" void kernel_launch(void* const* d_in, const int* in_sizes, int n_in,
                              void* d_out, int out_size, void* d_ws, size_t ws_size,
                              hipStream_t stream) {
  int i_inputs = 0, i_cb = 1, iA = 2, iB = 3;
  {
    int a = -1, b = -1, ii = -1, ic = -1;
    for (int i = 0; i < n_in; ++i) {
      if (in_sizes[i] == M_TOK * FEAT) ii = i;
      else if (in_sizes[i] == NQ * NCODE * DIM) ic = i;
      else if (in_sizes[i] == FEAT * DIM) { if (a < 0) a = i; else b = i; }
    }
    if (ii >= 0 && ic >= 0 && a >= 0 && b >= 0) { i_inputs = ii; i_cb = ic; iA = a; iB = b; }
  }
  const float* inputs = (const float*)d_in[i_inputs];
  const float* cb     = (const float*)d_in[i_cb];
  const float* w_in   = (const float*)d_in[iA];
  const float* w_out  = (const float*)d_in[iB];

  float* out       = (float*)d_out;
  float* quantized = out;                                 // 16384*756
  float* allq      = out + (size_t)M_TOK * FEAT;          // 8*16384*256
  float* idxout    = allq + (size_t)NQ * M_TOK * DIM;     // 16384*8

  // residual (16.8MB) lives in the quantized region (read once by k_vq8).
  float* residual = quantized;

  // Small scratch in d_ws (~4.8 MB). k_gemm_out reads only allq (output) + wT16 (ws).
  char* ws = (char*)d_ws;
  unsigned short*     cb16   = (unsigned short*)(ws);                 // 4,194,304 B
  unsigned short*     wT16   = (unsigned short*)(ws + 4194304);       //   393,216 B
  float*              cbn    = (float*)(ws + 4587520);                //    32,768 B

  k_z<<<M_TOK / 16, 256, 0, stream>>>(inputs, w_in, residual);
  k_cbnorm<<<NQ * NCODE / 256, 256, 0, stream>>>(cb, cbn);
  k_cb16<<<NQ * NCODE * DIM / 1024, 256, 0, stream>>>(cb, cb16);
  k_wt<<<768, 256, 0, stream>>>(w_out, wT16);
  k_vq8<<<M_TOK / 64, 512, 0, stream>>>(cb16, cb, cbn, residual, allq, idxout);
  k_gemm_out<<<M_TOK / 64, 256, 0, stream>>>(allq, wT16, quantized);
}